// Round 6
// baseline (398.968 us; speedup 1.0000x reference)
//
#include <hip/hip_runtime.h>
#include <hip/hip_bf16.h>

typedef __attribute__((ext_vector_type(8))) short bf16x8_t;
typedef __attribute__((ext_vector_type(16))) float f32x16_t;

__device__ __forceinline__ void gld16(void* lds, const void* g) {
    __builtin_amdgcn_global_load_lds(
        (const __attribute__((address_space(1))) void*)g,
        (__attribute__((address_space(3))) void*)lds, 16, 0, 0);
}

__device__ inline unsigned short f2bf(float f) {
    __hip_bfloat16 h = __float2bfloat16(f);
    return *reinterpret_cast<unsigned short*>(&h);
}

// ---------- transpose+convert 1024x1024 fp32 matrices (16 of them) -> bf16 ----------
__global__ __launch_bounds__(256) void transpose_kernel(
    const float* __restrict__ Wup, const float* __restrict__ Wdn,
    ushort* __restrict__ WtUp, ushort* __restrict__ WtDn)
{
    int z = blockIdx.z;
    const float* src = (z < 8) ? (Wup + ((size_t)z << 20)) : (Wdn + ((size_t)(z - 8) << 20));
    ushort* dst      = (z < 8) ? (WtUp + ((size_t)z << 20)) : (WtDn + ((size_t)(z - 8) << 20));
    __shared__ float tile[64][65];
    int x0 = blockIdx.x * 64, y0 = blockIdx.y * 64;
    int row = threadIdx.x >> 4, colq = threadIdx.x & 15;
#pragma unroll
    for (int it = 0; it < 4; it++) {
        int r = row + it * 16;
        float4 v = *(const float4*)(src + (size_t)(y0 + r) * 1024 + x0 + colq * 4);
        tile[r][colq * 4 + 0] = v.x; tile[r][colq * 4 + 1] = v.y;
        tile[r][colq * 4 + 2] = v.z; tile[r][colq * 4 + 3] = v.w;
    }
    __syncthreads();
#pragma unroll
    for (int it = 0; it < 4; it++) {
        int r = row + it * 16;
        ushort4 o;
        o.x = f2bf(tile[colq * 4 + 0][r]); o.y = f2bf(tile[colq * 4 + 1][r]);
        o.z = f2bf(tile[colq * 4 + 2][r]); o.w = f2bf(tile[colq * 4 + 3][r]);
        *(ushort4*)(dst + (size_t)(x0 + r) * 1024 + y0 + colq * 4) = o;
    }
}

// ---------------- router: logits, top-2, softmax + fused x->bf16 ----------------
__global__ __launch_bounds__(256) void router_kernel(
    const float* __restrict__ x, const float* __restrict__ rw,
    const float* __restrict__ rb, ushort* __restrict__ xb,
    int2* __restrict__ tok_e, float2* __restrict__ tok_w)
{
    int wave = threadIdx.x >> 6, lane = threadIdx.x & 63;
    int t = blockIdx.x * 4 + wave;
    float4 xv[4];
#pragma unroll
    for (int i = 0; i < 4; i++)
        xv[i] = *(const float4*)(x + (size_t)t * 1024 + i * 256 + lane * 4);
#pragma unroll
    for (int i = 0; i < 4; i++) {
        ushort4 o;
        o.x = f2bf(xv[i].x); o.y = f2bf(xv[i].y); o.z = f2bf(xv[i].z); o.w = f2bf(xv[i].w);
        *(ushort4*)(xb + (size_t)t * 1024 + i * 256 + lane * 4) = o;
    }
    float logit[8];
#pragma unroll
    for (int e = 0; e < 8; e++) {
        float s = 0.f;
#pragma unroll
        for (int i = 0; i < 4; i++) {
            float4 wv = *(const float4*)(rw + e * 1024 + i * 256 + lane * 4);
            s += xv[i].x * wv.x + xv[i].y * wv.y + xv[i].z * wv.z + xv[i].w * wv.w;
        }
#pragma unroll
        for (int m = 32; m >= 1; m >>= 1) s += __shfl_xor(s, m, 64);
        logit[e] = s + rb[e];
    }
    int i0 = 0;
#pragma unroll
    for (int e = 1; e < 8; e++) if (logit[e] > logit[i0]) i0 = e;
    int i1 = -1;
#pragma unroll
    for (int e = 0; e < 8; e++) if (e != i0 && (i1 < 0 || logit[e] > logit[i1])) i1 = e;
    float ev = expf(logit[i1] - logit[i0]);
    float s = 1.f + ev;
    if (lane == 0) {
        tok_e[t] = make_int2(i0, i1);
        tok_w[t] = make_float2(1.f / s, ev / s);
    }
}

// ---------------- per-block histograms ----------------
__global__ __launch_bounds__(256) void count_kernel(
    const int2* __restrict__ tok_e, const float2* __restrict__ tok_w,
    int* __restrict__ blockCnt, float* __restrict__ blockSum)
{
    __shared__ int lcnt[8];
    __shared__ float lsum[8];
    int tid = threadIdx.x;
    if (tid < 8) { lcnt[tid] = 0; lsum[tid] = 0.f; }
    __syncthreads();
    int t = blockIdx.x * 256 + tid;
    int2 e = tok_e[t]; float2 w = tok_w[t];
    atomicAdd(&lcnt[e.x], 1); atomicAdd(&lsum[e.x], w.x);
    atomicAdd(&lcnt[e.y], 1); atomicAdd(&lsum[e.y], w.y);
    __syncthreads();
    if (tid < 8) {
        blockCnt[blockIdx.x * 8 + tid] = lcnt[tid];
        blockSum[blockIdx.x * 8 + tid] = lsum[tid];
    }
}

// ---------------- scan: offsets, per-block bases, tile table, aux loss ----------------
__global__ void scan_kernel(const int* __restrict__ blockCnt,
                            const float* __restrict__ blockSum,
                            int* __restrict__ cnt, int* __restrict__ off,
                            int* __restrict__ base, int* __restrict__ tileE,
                            int* __restrict__ tileRow, int* __restrict__ nTiles,
                            float* aux_out)
{
    if (threadIdx.x == 0) {
        int tot[8]; float sw[8];
        for (int e = 0; e < 8; e++) { tot[e] = 0; sw[e] = 0.f; }
        for (int b = 0; b < 32; b++)
            for (int e = 0; e < 8; e++) { tot[e] += blockCnt[b * 8 + e]; sw[e] += blockSum[b * 8 + e]; }
        int o = 0; float aux = 0.f; int nT = 0;
        for (int e = 0; e < 8; e++) {
            cnt[e] = tot[e]; off[e] = o;
            aux += (float)tot[e] * sw[e];
            int run = o;
            for (int b = 0; b < 32; b++) { base[b * 8 + e] = run; run += blockCnt[b * 8 + e]; }
            for (int tt = 0; tt * 128 < tot[e]; tt++) { tileE[nT] = e; tileRow[nT] = o + tt * 128; nT++; }
            o += tot[e];
        }
        *nTiles = nT;
        aux *= 8.0f / (8192.0f * 8192.0f);
        *aux_out = aux;
    }
}

// ---------------- slot assignment (LDS-local ranks) + inverse map ----------------
__global__ __launch_bounds__(256) void assign_kernel(
    const int2* __restrict__ tok_e, const float2* __restrict__ tok_w,
    const int* __restrict__ base, int* __restrict__ pair_token,
    float* __restrict__ pair_w, int2* __restrict__ tokSlot)
{
    __shared__ int lcnt[8];
    int tid = threadIdx.x;
    if (tid < 8) lcnt[tid] = 0;
    __syncthreads();
    int t = blockIdx.x * 256 + tid;
    int2 e = tok_e[t]; float2 w = tok_w[t];
    int r0 = atomicAdd(&lcnt[e.x], 1);
    int r1 = atomicAdd(&lcnt[e.y], 1);
    int s0 = base[blockIdx.x * 8 + e.x] + r0;
    int s1 = base[blockIdx.x * 8 + e.y] + r1;
    pair_token[s0] = t; pair_w[s0] = w.x;
    pair_token[s1] = t; pair_w[s1] = w.y;
    tokSlot[t] = make_int2(s0, s1);
}

// ===================== GEMM core: 128x128 tile, 4 waves, 32x32x16 MFMA, BK=64 =====================
// LDS layout (fragment-ordered): chunk c (16B) at addr c*16.
//   A: chunk = (band*4 + s)*64 + half*32 + m   band=row/32, s=K16-step, half=k-half, m=row%32
//   Wave w stages A chunks [w*256, w*256+256): call j: lane L -> band=w, s=j, half=L>>5, m=L&31
// Frag read for (band,s): ds_read_b128 at ((band*4+s)*64 + lane)*16  — lane-linear, conflict-free.

template <bool UP>
__device__ __forceinline__ void gemm128_body(
    const ushort* __restrict__ Asrc_rows[],   // unused; kept simple below
    int dummy) {}

// -------- up GEMM: H = gelu(Xg @ Wup + bup) * w --------
__global__ __launch_bounds__(256, 4) void up_gemm(
    const ushort* __restrict__ xb, const ushort* __restrict__ WtUp,
    const float* __restrict__ bup,
    const int* __restrict__ cnt, const int* __restrict__ off,
    const int* __restrict__ nTiles, const int* __restrict__ tileE,
    const int* __restrict__ tileRow,
    const int* __restrict__ pair_token, const float* __restrict__ pair_w,
    const ushort* __restrict__ zeroPage, ushort* __restrict__ Hbuf)
{
    if ((int)blockIdx.y >= *nTiles) return;
    int e = tileE[blockIdx.y];
    int rowBase = tileRow[blockIdx.y];
    int expertEnd = off[e] + cnt[e];
    int colBase = blockIdx.x * 128;
    const ushort* Bsrc = WtUp + ((size_t)e << 20);

    __shared__ ushort As[128 * 64];   // 16 KB
    __shared__ ushort Bs[128 * 64];   // 16 KB

    int tid = threadIdx.x, w = tid >> 6, lane = tid & 63;
    int half = lane >> 5, m = lane & 31;
    int wm = w & 1, wn = w >> 1;

    // staging row for this lane (band = w)
    int gA = rowBase + w * 32 + m;
    const ushort* aRow = (gA < expertEnd) ? xb + (size_t)pair_token[gA] * 1024 : zeroPage;
    const ushort* aP = aRow + half * 8;
    const ushort* bP = Bsrc + (size_t)(colBase + w * 32 + m) * 1024 + half * 8;
    ushort* lA = &As[w * 2048];   // w*256 chunks * 8 ushorts
    ushort* lB = &Bs[w * 2048];

    f32x16_t acc[2][2];
#pragma unroll
    for (int i = 0; i < 2; i++)
#pragma unroll
        for (int j = 0; j < 2; j++)
#pragma unroll
            for (int p = 0; p < 16; p++) acc[i][j][p] = 0.f;

    for (int kk = 0; kk < 1024; kk += 64) {
#pragma unroll
        for (int j = 0; j < 4; j++) {
            gld16(lA + j * 512, aP + kk + j * 16);
            gld16(lB + j * 512, bP + kk + j * 16);
        }
        __syncthreads();
#pragma unroll
        for (int s = 0; s < 4; s++) {
            bf16x8_t a[2], b[2];
#pragma unroll
            for (int i = 0; i < 2; i++)
                a[i] = *(const bf16x8_t*)&As[(((wm * 2 + i) * 4 + s) * 64 + lane) * 8];
#pragma unroll
            for (int j = 0; j < 2; j++)
                b[j] = *(const bf16x8_t*)&Bs[(((wn * 2 + j) * 4 + s) * 64 + lane) * 8];
#pragma unroll
            for (int i = 0; i < 2; i++)
#pragma unroll
                for (int j = 0; j < 2; j++)
                    acc[i][j] = __builtin_amdgcn_mfma_f32_32x32x16_bf16(a[i], b[j], acc[i][j], 0, 0, 0);
        }
        __syncthreads();
    }

    // epilogue: C/D layout col=lane&31, row=(p&3)+8*(p>>2)+4*half
#pragma unroll
    for (int i = 0; i < 2; i++) {
#pragma unroll
        for (int p = 0; p < 16; p++) {
            int rl = (p & 3) + 8 * (p >> 2) + 4 * half;
            int gRow = rowBase + (wm * 2 + i) * 32 + rl;
            if (gRow < expertEnd) {
                float wgt = pair_w[gRow];
#pragma unroll
                for (int j = 0; j < 2; j++) {
                    int col = colBase + (wn * 2 + j) * 32 + m;
                    float h = acc[i][j][p] + bup[e * 1024 + col];
                    float g = 0.5f * h * (1.0f + erff(h * 0.70710678118654752f));
                    Hbuf[(size_t)gRow * 1024 + col] = f2bf(g * wgt);
                }
            }
        }
    }
}

// -------- down GEMM: pairOut = H @ Wdn (bf16, no atomics) --------
__global__ __launch_bounds__(256, 4) void down_gemm(
    const ushort* __restrict__ Hbuf, const ushort* __restrict__ WtDn,
    const int* __restrict__ cnt, const int* __restrict__ off,
    const int* __restrict__ nTiles, const int* __restrict__ tileE,
    const int* __restrict__ tileRow,
    const ushort* __restrict__ zeroPage, ushort* __restrict__ pairOut)
{
    if ((int)blockIdx.y >= *nTiles) return;
    int e = tileE[blockIdx.y];
    int rowBase = tileRow[blockIdx.y];
    int expertEnd = off[e] + cnt[e];
    int colBase = blockIdx.x * 128;
    const ushort* Bsrc = WtDn + ((size_t)e << 20);

    __shared__ ushort As[128 * 64];
    __shared__ ushort Bs[128 * 64];

    int tid = threadIdx.x, w = tid >> 6, lane = tid & 63;
    int half = lane >> 5, m = lane & 31;
    int wm = w & 1, wn = w >> 1;

    int gA = rowBase + w * 32 + m;
    const ushort* aRow = (gA < expertEnd) ? Hbuf + (size_t)gA * 1024 : zeroPage;
    const ushort* aP = aRow + half * 8;
    const ushort* bP = Bsrc + (size_t)(colBase + w * 32 + m) * 1024 + half * 8;
    ushort* lA = &As[w * 2048];
    ushort* lB = &Bs[w * 2048];

    f32x16_t acc[2][2];
#pragma unroll
    for (int i = 0; i < 2; i++)
#pragma unroll
        for (int j = 0; j < 2; j++)
#pragma unroll
            for (int p = 0; p < 16; p++) acc[i][j][p] = 0.f;

    for (int kk = 0; kk < 1024; kk += 64) {
#pragma unroll
        for (int j = 0; j < 4; j++) {
            gld16(lA + j * 512, aP + kk + j * 16);
            gld16(lB + j * 512, bP + kk + j * 16);
        }
        __syncthreads();
#pragma unroll
        for (int s = 0; s < 4; s++) {
            bf16x8_t a[2], b[2];
#pragma unroll
            for (int i = 0; i < 2; i++)
                a[i] = *(const bf16x8_t*)&As[(((wm * 2 + i) * 4 + s) * 64 + lane) * 8];
#pragma unroll
            for (int j = 0; j < 2; j++)
                b[j] = *(const bf16x8_t*)&Bs[(((wn * 2 + j) * 4 + s) * 64 + lane) * 8];
#pragma unroll
            for (int i = 0; i < 2; i++)
#pragma unroll
                for (int j = 0; j < 2; j++)
                    acc[i][j] = __builtin_amdgcn_mfma_f32_32x32x16_bf16(a[i], b[j], acc[i][j], 0, 0, 0);
        }
        __syncthreads();
    }

#pragma unroll
    for (int i = 0; i < 2; i++) {
#pragma unroll
        for (int p = 0; p < 16; p++) {
            int rl = (p & 3) + 8 * (p >> 2) + 4 * half;
            int gRow = rowBase + (wm * 2 + i) * 32 + rl;
            if (gRow < expertEnd) {
#pragma unroll
                for (int j = 0; j < 2; j++) {
                    int col = colBase + (wn * 2 + j) * 32 + m;
                    pairOut[(size_t)gRow * 1024 + col] = f2bf(acc[i][j][p]);
                }
            }
        }
    }
}

// ---------------- finalize ----------------
__global__ __launch_bounds__(256) void finalize_kernel(
    const ushort* __restrict__ pairOut, const int2* __restrict__ tokSlot,
    const int2* __restrict__ tok_e, const float2* __restrict__ tok_w,
    const float* __restrict__ bdn, float* __restrict__ out)
{
    int t = blockIdx.x;
    int2 s = tokSlot[t]; int2 e = tok_e[t]; float2 w = tok_w[t];
    int c = threadIdx.x * 4;
    ushort4 p0 = *(const ushort4*)(pairOut + (size_t)s.x * 1024 + c);
    ushort4 p1 = *(const ushort4*)(pairOut + (size_t)s.y * 1024 + c);
    float4 b0 = *(const float4*)(bdn + (size_t)e.x * 1024 + c);
    float4 b1 = *(const float4*)(bdn + (size_t)e.y * 1024 + c);
    __hip_bfloat16* h0 = (__hip_bfloat16*)&p0;
    __hip_bfloat16* h1 = (__hip_bfloat16*)&p1;
    float4 o;
    o.x = __bfloat162float(h0[0]) + __bfloat162float(h1[0]) + w.x * b0.x + w.y * b1.x;
    o.y = __bfloat162float(h0[1]) + __bfloat162float(h1[1]) + w.x * b0.y + w.y * b1.y;
    o.z = __bfloat162float(h0[2]) + __bfloat162float(h1[2]) + w.x * b0.z + w.y * b1.z;
    o.w = __bfloat162float(h0[3]) + __bfloat162float(h1[3]) + w.x * b0.w + w.y * b1.w;
    *(float4*)(out + (size_t)t * 1024 + c) = o;
}

extern "C" void kernel_launch(void* const* d_in, const int* in_sizes, int n_in,
                              void* d_out, int out_size, void* d_ws, size_t ws_size,
                              hipStream_t stream) {
    const float* x   = (const float*)d_in[0];
    const float* rw  = (const float*)d_in[1];
    const float* rb  = (const float*)d_in[2];
    const float* Wup = (const float*)d_in[3];
    const float* bup = (const float*)d_in[4];
    const float* Wdn = (const float*)d_in[5];
    const float* bdn = (const float*)d_in[6];
    float* out = (float*)d_out;

    char* ws = (char*)d_ws;
    int*    cnt      = (int*)(ws + 0);
    int*    off      = (int*)(ws + 64);
    int*    nTiles   = (int*)(ws + 128);
    int*    blockCnt = (int*)(ws + 256);    // 1 KB
    float*  blockSum = (float*)(ws + 1536); // 1 KB
    int*    base     = (int*)(ws + 2816);   // 1 KB
    int*    tileE    = (int*)(ws + 4096);   // 640 B
    int*    tileRow  = (int*)(ws + 4736);   // 640 B
    ushort* zeroPage = (ushort*)(ws + 8192);            // 4 KB
    int2*   tok_e    = (int2*)(ws + 12288);             // 64 KB
    float2* tok_w    = (float2*)(ws + 77824);           // 64 KB
    int2*   tokSlot  = (int2*)(ws + 143360);            // 64 KB
    int*    pair_token = (int*)(ws + 208896);           // 64 KB
    float*  pair_w     = (float*)(ws + 274432);         // 64 KB
    char* big = ws + 1048576;
    ushort* Hbuf    = (ushort*)big;                     // 33554432
    ushort* pairOut = (ushort*)(big + 33554432);        // 33554432
    ushort* WtUp    = (ushort*)(big + 67108864);        // 16777216
    ushort* WtDn    = (ushort*)(big + 83886080);        // 16777216
    ushort* xb      = (ushort*)(big + 100663296);       // 16777216

    hipMemsetAsync(zeroPage, 0, 4096, stream);

    transpose_kernel<<<dim3(16, 16, 16), 256, 0, stream>>>(Wup, Wdn, WtUp, WtDn);
    router_kernel<<<2048, 256, 0, stream>>>(x, rw, rb, xb, tok_e, tok_w);
    count_kernel<<<32, 256, 0, stream>>>(tok_e, tok_w, blockCnt, blockSum);
    scan_kernel<<<1, 64, 0, stream>>>(blockCnt, blockSum, cnt, off, base,
                                      tileE, tileRow, nTiles, out + 8388608);
    assign_kernel<<<32, 256, 0, stream>>>(tok_e, tok_w, base, pair_token, pair_w, tokSlot);
    up_gemm<<<dim3(8, 136), 256, 0, stream>>>(
        xb, WtUp, bup, cnt, off, nTiles, tileE, tileRow, pair_token, pair_w, zeroPage, Hbuf);
    down_gemm<<<dim3(8, 136), 256, 0, stream>>>(
        Hbuf, WtDn, cnt, off, nTiles, tileE, tileRow, zeroPage, pairOut);
    finalize_kernel<<<8192, 256, 0, stream>>>(pairOut, tokSlot, tok_e, tok_w, bdn, out);
}

// Round 7
// 345.388 us; speedup vs baseline: 1.1551x; 1.1551x over previous
//
#include <hip/hip_runtime.h>
#include <hip/hip_bf16.h>

typedef __attribute__((ext_vector_type(8))) short bf16x8_t;
typedef __attribute__((ext_vector_type(4))) float f32x4_t;

__device__ __forceinline__ void gld16(void* lds, const void* g) {
    __builtin_amdgcn_global_load_lds(
        (const __attribute__((address_space(1))) void*)g,
        (__attribute__((address_space(3))) void*)lds, 16, 0, 0);
}

__device__ inline unsigned short f2bf(float f) {
    __hip_bfloat16 h = __float2bfloat16(f);
    return *reinterpret_cast<unsigned short*>(&h);
}

// tanh-approx GELU: h * sigmoid(2u), u = 0.79788456*(h + 0.044715 h^3)
__device__ __forceinline__ float gelu_fast(float h) {
    float u = 0.7978845608028654f * h * (1.0f + 0.044715f * h * h);
    return h / (1.0f + __expf(-2.0f * u));
}

// ---------- transpose+convert 1024x1024 fp32 matrices (16 of them) -> bf16 ----------
__global__ __launch_bounds__(256) void transpose_kernel(
    const float* __restrict__ Wup, const float* __restrict__ Wdn,
    ushort* __restrict__ WtUp, ushort* __restrict__ WtDn)
{
    int z = blockIdx.z;
    const float* src = (z < 8) ? (Wup + ((size_t)z << 20)) : (Wdn + ((size_t)(z - 8) << 20));
    ushort* dst      = (z < 8) ? (WtUp + ((size_t)z << 20)) : (WtDn + ((size_t)(z - 8) << 20));
    __shared__ float tile[64][65];
    int x0 = blockIdx.x * 64, y0 = blockIdx.y * 64;
    int row = threadIdx.x >> 4, colq = threadIdx.x & 15;
#pragma unroll
    for (int it = 0; it < 4; it++) {
        int r = row + it * 16;
        float4 v = *(const float4*)(src + (size_t)(y0 + r) * 1024 + x0 + colq * 4);
        tile[r][colq * 4 + 0] = v.x; tile[r][colq * 4 + 1] = v.y;
        tile[r][colq * 4 + 2] = v.z; tile[r][colq * 4 + 3] = v.w;
    }
    __syncthreads();
#pragma unroll
    for (int it = 0; it < 4; it++) {
        int r = row + it * 16;
        ushort4 o;
        o.x = f2bf(tile[colq * 4 + 0][r]); o.y = f2bf(tile[colq * 4 + 1][r]);
        o.z = f2bf(tile[colq * 4 + 2][r]); o.w = f2bf(tile[colq * 4 + 3][r]);
        *(ushort4*)(dst + (size_t)(x0 + r) * 1024 + y0 + colq * 4) = o;
    }
}

// ---------------- router: logits, top-2, softmax + fused x->bf16 ----------------
__global__ __launch_bounds__(256) void router_kernel(
    const float* __restrict__ x, const float* __restrict__ rw,
    const float* __restrict__ rb, ushort* __restrict__ xb,
    int2* __restrict__ tok_e, float2* __restrict__ tok_w)
{
    int wave = threadIdx.x >> 6, lane = threadIdx.x & 63;
    int t = blockIdx.x * 4 + wave;
    float4 xv[4];
#pragma unroll
    for (int i = 0; i < 4; i++)
        xv[i] = *(const float4*)(x + (size_t)t * 1024 + i * 256 + lane * 4);
#pragma unroll
    for (int i = 0; i < 4; i++) {
        ushort4 o;
        o.x = f2bf(xv[i].x); o.y = f2bf(xv[i].y); o.z = f2bf(xv[i].z); o.w = f2bf(xv[i].w);
        *(ushort4*)(xb + (size_t)t * 1024 + i * 256 + lane * 4) = o;
    }
    float logit[8];
#pragma unroll
    for (int e = 0; e < 8; e++) {
        float s = 0.f;
#pragma unroll
        for (int i = 0; i < 4; i++) {
            float4 wv = *(const float4*)(rw + e * 1024 + i * 256 + lane * 4);
            s += xv[i].x * wv.x + xv[i].y * wv.y + xv[i].z * wv.z + xv[i].w * wv.w;
        }
#pragma unroll
        for (int m = 32; m >= 1; m >>= 1) s += __shfl_xor(s, m, 64);
        logit[e] = s + rb[e];
    }
    int i0 = 0;
#pragma unroll
    for (int e = 1; e < 8; e++) if (logit[e] > logit[i0]) i0 = e;
    int i1 = -1;
#pragma unroll
    for (int e = 0; e < 8; e++) if (e != i0 && (i1 < 0 || logit[e] > logit[i1])) i1 = e;
    float ev = expf(logit[i1] - logit[i0]);
    float s = 1.f + ev;
    if (lane == 0) {
        tok_e[t] = make_int2(i0, i1);
        tok_w[t] = make_float2(1.f / s, ev / s);
    }
}

// ---------------- per-block histograms ----------------
__global__ __launch_bounds__(256) void count_kernel(
    const int2* __restrict__ tok_e, const float2* __restrict__ tok_w,
    int* __restrict__ blockCnt, float* __restrict__ blockSum)
{
    __shared__ int lcnt[8];
    __shared__ float lsum[8];
    int tid = threadIdx.x;
    if (tid < 8) { lcnt[tid] = 0; lsum[tid] = 0.f; }
    __syncthreads();
    int t = blockIdx.x * 256 + tid;
    int2 e = tok_e[t]; float2 w = tok_w[t];
    atomicAdd(&lcnt[e.x], 1); atomicAdd(&lsum[e.x], w.x);
    atomicAdd(&lcnt[e.y], 1); atomicAdd(&lsum[e.y], w.y);
    __syncthreads();
    if (tid < 8) {
        blockCnt[blockIdx.x * 8 + tid] = lcnt[tid];
        blockSum[blockIdx.x * 8 + tid] = lsum[tid];
    }
}

// ---------------- scan: offsets, per-block bases, tile table, aux loss ----------------
__global__ void scan_kernel(const int* __restrict__ blockCnt,
                            const float* __restrict__ blockSum,
                            int* __restrict__ cnt, int* __restrict__ off,
                            int* __restrict__ base, int* __restrict__ tileE,
                            int* __restrict__ tileRow, int* __restrict__ nTiles,
                            float* aux_out)
{
    if (threadIdx.x == 0) {
        int tot[8]; float sw[8];
        for (int e = 0; e < 8; e++) { tot[e] = 0; sw[e] = 0.f; }
        for (int b = 0; b < 32; b++)
            for (int e = 0; e < 8; e++) { tot[e] += blockCnt[b * 8 + e]; sw[e] += blockSum[b * 8 + e]; }
        int o = 0; float aux = 0.f; int nT = 0;
        for (int e = 0; e < 8; e++) {
            cnt[e] = tot[e]; off[e] = o;
            aux += (float)tot[e] * sw[e];
            int run = o;
            for (int b = 0; b < 32; b++) { base[b * 8 + e] = run; run += blockCnt[b * 8 + e]; }
            for (int tt = 0; tt * 128 < tot[e]; tt++) { tileE[nT] = e; tileRow[nT] = o + tt * 128; nT++; }
            o += tot[e];
        }
        *nTiles = nT;
        aux *= 8.0f / (8192.0f * 8192.0f);
        *aux_out = aux;
    }
}

// ---------------- slot assignment (LDS-local ranks) + inverse map ----------------
__global__ __launch_bounds__(256) void assign_kernel(
    const int2* __restrict__ tok_e, const float2* __restrict__ tok_w,
    const int* __restrict__ base, int* __restrict__ pair_token,
    float* __restrict__ pair_w, int2* __restrict__ tokSlot)
{
    __shared__ int lcnt[8];
    int tid = threadIdx.x;
    if (tid < 8) lcnt[tid] = 0;
    __syncthreads();
    int t = blockIdx.x * 256 + tid;
    int2 e = tok_e[t]; float2 w = tok_w[t];
    int r0 = atomicAdd(&lcnt[e.x], 1);
    int r1 = atomicAdd(&lcnt[e.y], 1);
    int s0 = base[blockIdx.x * 8 + e.x] + r0;
    int s1 = base[blockIdx.x * 8 + e.y] + r1;
    pair_token[s0] = t; pair_w[s0] = w.x;
    pair_token[s1] = t; pair_w[s1] = w.y;
    tokSlot[t] = make_int2(s0, s1);
}

// ======== GEMM: 128x128 tile, 8 waves, 16x16x32 MFMA, BK=32, XOR-swizzled LDS ========
// LDS: row-major 32-ushort rows; chunk (row, q) lives at slot row*4 + (q ^ (row&3)).
// Staging: lane stages (row = w*16 + (lane>>2), slot-q = lane&3) -> global chunk
//   qg = (lane&3) ^ (row&3); 4 lanes/row still cover 64B contiguously (permuted).
// Frag read (row, q): ushort addr = row*32 + ((q ^ (row&3))*8) — spreads bank spans.

// -------- up GEMM: H = gelu(Xg @ Wup + bup) * w --------
__global__ __launch_bounds__(512, 4) void up_gemm(
    const ushort* __restrict__ xb, const ushort* __restrict__ WtUp,
    const float* __restrict__ bup,
    const int* __restrict__ cnt, const int* __restrict__ off,
    const int* __restrict__ nTiles, const int* __restrict__ tileE,
    const int* __restrict__ tileRow,
    const int* __restrict__ pair_token, const float* __restrict__ pair_w,
    const ushort* __restrict__ zeroPage, ushort* __restrict__ Hbuf)
{
    if ((int)blockIdx.y >= *nTiles) return;
    int e = tileE[blockIdx.y];
    int rowBase = tileRow[blockIdx.y];
    int expertEnd = off[e] + cnt[e];
    int colBase = blockIdx.x * 128;
    const ushort* Bsrc = WtUp + ((size_t)e << 20);

    __shared__ ushort As[128 * 32];
    __shared__ ushort Bs[128 * 32];

    int tid = threadIdx.x, w = tid >> 6, lane = tid & 63;
    int q = lane >> 4, r = lane & 15;
    int wm = w & 3, wn = w >> 2;

    int sr = lane >> 2;
    int rowL = w * 16 + sr;
    int qg = (lane & 3) ^ (sr & 3);
    int cOff = qg * 8;
    int gA = rowBase + rowL;

    const ushort* aP = (gA < expertEnd) ? xb + (size_t)pair_token[gA] * 1024 + cOff : zeroPage + cOff;
    const ushort* bP = Bsrc + (size_t)(colBase + rowL) * 1024 + cOff;

    ushort* lA = &As[w * 512];   // = lane-linear dst: As[w*512 + lane*8]
    ushort* lB = &Bs[w * 512];

    f32x4_t acc[2][4];
#pragma unroll
    for (int i = 0; i < 2; i++)
#pragma unroll
        for (int j = 0; j < 4; j++) { acc[i][j][0] = 0.f; acc[i][j][1] = 0.f; acc[i][j][2] = 0.f; acc[i][j][3] = 0.f; }

    for (int kk = 0; kk < 1024; kk += 32) {
        gld16(lA, aP + kk);
        gld16(lB, bP + kk);
        __syncthreads();
        bf16x8_t a[2], b[4];
#pragma unroll
        for (int i = 0; i < 2; i++) {
            int ra = wm * 32 + i * 16 + r;
            a[i] = *(const bf16x8_t*)&As[ra * 32 + ((q ^ (ra & 3)) * 8)];
        }
#pragma unroll
        for (int j = 0; j < 4; j++) {
            int rb2 = wn * 64 + j * 16 + r;
            b[j] = *(const bf16x8_t*)&Bs[rb2 * 32 + ((q ^ (rb2 & 3)) * 8)];
        }
#pragma unroll
        for (int i = 0; i < 2; i++)
#pragma unroll
            for (int j = 0; j < 4; j++)
                acc[i][j] = __builtin_amdgcn_mfma_f32_16x16x32_bf16(a[i], b[j], acc[i][j], 0, 0, 0);
        __syncthreads();
    }

#pragma unroll
    for (int j = 0; j < 4; j++) {
        int col = colBase + wn * 64 + j * 16 + r;
        float bias = bup[e * 1024 + col];
#pragma unroll
        for (int i = 0; i < 2; i++) {
#pragma unroll
            for (int reg = 0; reg < 4; reg++) {
                int gRow = rowBase + wm * 32 + i * 16 + q * 4 + reg;
                if (gRow < expertEnd) {
                    float h = acc[i][j][reg] + bias;
                    Hbuf[(size_t)gRow * 1024 + col] = f2bf(gelu_fast(h) * pair_w[gRow]);
                }
            }
        }
    }
}

// -------- down GEMM: pairOut = H @ Wdn + w*bdn[e]  (bf16, no atomics) --------
__global__ __launch_bounds__(512, 4) void down_gemm(
    const ushort* __restrict__ Hbuf, const ushort* __restrict__ WtDn,
    const float* __restrict__ bdn,
    const int* __restrict__ cnt, const int* __restrict__ off,
    const int* __restrict__ nTiles, const int* __restrict__ tileE,
    const int* __restrict__ tileRow, const float* __restrict__ pair_w,
    const ushort* __restrict__ zeroPage, ushort* __restrict__ pairOut)
{
    if ((int)blockIdx.y >= *nTiles) return;
    int e = tileE[blockIdx.y];
    int rowBase = tileRow[blockIdx.y];
    int expertEnd = off[e] + cnt[e];
    int colBase = blockIdx.x * 128;
    const ushort* Bsrc = WtDn + ((size_t)e << 20);

    __shared__ ushort As[128 * 32];
    __shared__ ushort Bs[128 * 32];

    int tid = threadIdx.x, w = tid >> 6, lane = tid & 63;
    int q = lane >> 4, r = lane & 15;
    int wm = w & 3, wn = w >> 2;

    int sr = lane >> 2;
    int rowL = w * 16 + sr;
    int qg = (lane & 3) ^ (sr & 3);
    int cOff = qg * 8;
    int gA = rowBase + rowL;

    const ushort* aP = (gA < expertEnd) ? Hbuf + (size_t)gA * 1024 + cOff : zeroPage + cOff;
    const ushort* bP = Bsrc + (size_t)(colBase + rowL) * 1024 + cOff;

    ushort* lA = &As[w * 512];
    ushort* lB = &Bs[w * 512];

    f32x4_t acc[2][4];
#pragma unroll
    for (int i = 0; i < 2; i++)
#pragma unroll
        for (int j = 0; j < 4; j++) { acc[i][j][0] = 0.f; acc[i][j][1] = 0.f; acc[i][j][2] = 0.f; acc[i][j][3] = 0.f; }

    for (int kk = 0; kk < 1024; kk += 32) {
        gld16(lA, aP + kk);
        gld16(lB, bP + kk);
        __syncthreads();
        bf16x8_t a[2], b[4];
#pragma unroll
        for (int i = 0; i < 2; i++) {
            int ra = wm * 32 + i * 16 + r;
            a[i] = *(const bf16x8_t*)&As[ra * 32 + ((q ^ (ra & 3)) * 8)];
        }
#pragma unroll
        for (int j = 0; j < 4; j++) {
            int rb2 = wn * 64 + j * 16 + r;
            b[j] = *(const bf16x8_t*)&Bs[rb2 * 32 + ((q ^ (rb2 & 3)) * 8)];
        }
#pragma unroll
        for (int i = 0; i < 2; i++)
#pragma unroll
            for (int j = 0; j < 4; j++)
                acc[i][j] = __builtin_amdgcn_mfma_f32_16x16x32_bf16(a[i], b[j], acc[i][j], 0, 0, 0);
        __syncthreads();
    }

#pragma unroll
    for (int j = 0; j < 4; j++) {
        int col = colBase + wn * 64 + j * 16 + r;
        float bias = bdn[e * 1024 + col];
#pragma unroll
        for (int i = 0; i < 2; i++) {
#pragma unroll
            for (int reg = 0; reg < 4; reg++) {
                int gRow = rowBase + wm * 32 + i * 16 + q * 4 + reg;
                if (gRow < expertEnd)
                    pairOut[(size_t)gRow * 1024 + col] = f2bf(acc[i][j][reg] + pair_w[gRow] * bias);
            }
        }
    }
}

// ---------------- finalize: out[t] = pairOut[s0] + pairOut[s1] ----------------
__global__ __launch_bounds__(256) void finalize_kernel(
    const ushort* __restrict__ pairOut, const int2* __restrict__ tokSlot,
    float* __restrict__ out)
{
    int t = blockIdx.x;
    int2 s = tokSlot[t];
    int c = threadIdx.x * 4;
    ushort4 p0 = *(const ushort4*)(pairOut + (size_t)s.x * 1024 + c);
    ushort4 p1 = *(const ushort4*)(pairOut + (size_t)s.y * 1024 + c);
    __hip_bfloat16* h0 = (__hip_bfloat16*)&p0;
    __hip_bfloat16* h1 = (__hip_bfloat16*)&p1;
    float4 o;
    o.x = __bfloat162float(h0[0]) + __bfloat162float(h1[0]);
    o.y = __bfloat162float(h0[1]) + __bfloat162float(h1[1]);
    o.z = __bfloat162float(h0[2]) + __bfloat162float(h1[2]);
    o.w = __bfloat162float(h0[3]) + __bfloat162float(h1[3]);
    *(float4*)(out + (size_t)t * 1024 + c) = o;
}

extern "C" void kernel_launch(void* const* d_in, const int* in_sizes, int n_in,
                              void* d_out, int out_size, void* d_ws, size_t ws_size,
                              hipStream_t stream) {
    const float* x   = (const float*)d_in[0];
    const float* rw  = (const float*)d_in[1];
    const float* rb  = (const float*)d_in[2];
    const float* Wup = (const float*)d_in[3];
    const float* bup = (const float*)d_in[4];
    const float* Wdn = (const float*)d_in[5];
    const float* bdn = (const float*)d_in[6];
    float* out = (float*)d_out;

    char* ws = (char*)d_ws;
    int*    cnt      = (int*)(ws + 0);
    int*    off      = (int*)(ws + 64);
    int*    nTiles   = (int*)(ws + 128);
    int*    blockCnt = (int*)(ws + 256);    // 1 KB
    float*  blockSum = (float*)(ws + 1536); // 1 KB
    int*    base     = (int*)(ws + 2816);   // 1 KB
    int*    tileE    = (int*)(ws + 4096);   // 640 B
    int*    tileRow  = (int*)(ws + 4736);   // 640 B
    ushort* zeroPage = (ushort*)(ws + 8192);            // 4 KB
    int2*   tok_e    = (int2*)(ws + 12288);             // 64 KB
    float2* tok_w    = (float2*)(ws + 77824);           // 64 KB
    int2*   tokSlot  = (int2*)(ws + 143360);            // 64 KB
    int*    pair_token = (int*)(ws + 208896);           // 64 KB
    float*  pair_w     = (float*)(ws + 274432);         // 64 KB
    char* big = ws + 1048576;
    ushort* Hbuf    = (ushort*)big;                     // 33554432
    ushort* pairOut = (ushort*)(big + 33554432);        // 33554432
    ushort* WtUp    = (ushort*)(big + 67108864);        // 16777216
    ushort* WtDn    = (ushort*)(big + 83886080);        // 16777216
    ushort* xb      = (ushort*)(big + 100663296);       // 16777216

    hipMemsetAsync(zeroPage, 0, 4096, stream);

    transpose_kernel<<<dim3(16, 16, 16), 256, 0, stream>>>(Wup, Wdn, WtUp, WtDn);
    router_kernel<<<2048, 256, 0, stream>>>(x, rw, rb, xb, tok_e, tok_w);
    count_kernel<<<32, 256, 0, stream>>>(tok_e, tok_w, blockCnt, blockSum);
    scan_kernel<<<1, 64, 0, stream>>>(blockCnt, blockSum, cnt, off, base,
                                      tileE, tileRow, nTiles, out + 8388608);
    assign_kernel<<<32, 256, 0, stream>>>(tok_e, tok_w, base, pair_token, pair_w, tokSlot);
    up_gemm<<<dim3(8, 136), 512, 0, stream>>>(
        xb, WtUp, bup, cnt, off, nTiles, tileE, tileRow, pair_token, pair_w, zeroPage, Hbuf);
    down_gemm<<<dim3(8, 136), 512, 0, stream>>>(
        Hbuf, WtDn, bdn, cnt, off, nTiles, tileE, tileRow, pair_w, zeroPage, pairOut);
    finalize_kernel<<<8192, 256, 0, stream>>>(pairOut, tokSlot, out);
}